// Round 14
// baseline (173.600 us; speedup 1.0000x reference)
//
#include <hip/hip_runtime.h>
#include <math.h>

#define BB   512
#define CC   3
#define HH   64
#define WW   32
#define HOUT 38
#define WOUT 16
#define HID  128
#define DD   114               // CC*HOUT
#define SEQP 120               // seq row stride (480 B, 16B-aligned)
#define NPOOL (CC*HOUT*WOUT)   // 1824

typedef float f32x4 __attribute__((ext_vector_type(4)));
typedef float f32x2 __attribute__((ext_vector_type(2)));

// fast tanh on the serial chain: exact saturation at +/-inf, ~1e-6 abs error
__device__ __forceinline__ float fast_tanh(float u) {
    return 1.f - 2.f / (__expf(2.f * u) + 1.f);
}

// async 16B global->LDS (HW scatters lane i to ldsbase + i*16)
__device__ __forceinline__ void gl_lds16(const void* g, void* l) {
    __builtin_amdgcn_global_load_lds(
        (const __attribute__((address_space(1))) unsigned int*)g,
        (__attribute__((address_space(3))) unsigned int*)l, 16, 0, 0);
}

// ws layout (floats)
#define WS_SMEAN 0
#define WS_TMEAN 512

// ---- wave-solo per-batch kernel --------------------------------------------
// 512 blocks x 64 threads (ONE wave per batch). Lane l owns output rows l and
// l+64 with FULL K in registers -> no split-K combine, no cross-wave exchange.
// Barriers are single-wave (cheap). Wih arrives via async global_load_lds;
// Whh is gathered straight into 256 VGPRs under the projection.
__global__ __launch_bounds__(64, 1)
void k1_wave(const float* __restrict__ x,
             const float* __restrict__ Wih,
             const float* __restrict__ Whh,
             const float* __restrict__ bih,
             const float* __restrict__ bhh,
             float* __restrict__ s_mean,
             float* __restrict__ t_mean)
{
    __shared__ __align__(16) float wihl[HID * DD];   // 58368 B, linear rows
    __shared__ __align__(16) float seq[WOUT][SEQP];  // 7.7 KB
    __shared__ __align__(16) float hbuf[2][HID];     // 1 KB

    const int l = threadIdx.x;           // 0..63
    const int b = blockIdx.x;

    // --- issue async Wih -> LDS first (57 x 1KB); completes under pool ---
    #pragma unroll
    for (int i = 0; i < 57; ++i)
        gl_lds16((const char*)Wih + (size_t)(i*64 + l)*16,
                 (char*)wihl + i*1024);

    // --- pool (2x2 fractional max) + exact GELU; x gathered from global ---
    const float* xb = x + (size_t)b * (CC*HH*WW);
    const double alpha = (double)(HH - 2) / (double)(HOUT - 1);
    const double f05   = floor(0.5 * alpha);
    float ps = 0.f;
    #pragma unroll
    for (int it = 0; it < 29; ++it) {
        int idx = l + 64*it;
        if (idx < NPOOL) {
            int c  = idx / (HOUT*WOUT);
            int r  = idx % (HOUT*WOUT);
            int ho = r / WOUT;
            int wo = r % WOUT;
            int r0 = (ho < HOUT-1) ? (int)(floor((ho + 0.5)*alpha) - f05)
                                   : (HH - 2);
            const float* p = xb + c*(HH*WW) + r0*WW + 2*wo;   // 8B-aligned
            f32x2 u0 = *(const f32x2*)p;
            f32x2 u1 = *(const f32x2*)(p + WW);
            float m = fmaxf(fmaxf(u0.x, u0.y), fmaxf(u1.x, u1.y));
            ps += m;
            seq[wo][c*HOUT + ho] =
                0.5f * m * (1.f + erff(m * 0.70710678118654752440f));
        }
    }
    #pragma unroll
    for (int off = 32; off > 0; off >>= 1) ps += __shfl_down(ps, off);
    if (l == 0) s_mean[b] = ps * (1.f / (float)NPOOL);

    hbuf[0][l] = 0.f;  hbuf[0][64 + l] = 0.f;        // h_0 = 0

    __syncthreads();   // 1-wave barrier: drains wih global_load_lds + seq/hbuf

    // --- Whh gather -> 256 VGPRs (rows l, l+64; 16B-aligned, L2-resident) ---
    f32x4 whA[32], whB[32];
    {
        const f32x4* ra = (const f32x4*)(Whh + (size_t)l * HID);
        const f32x4* rb = (const f32x4*)(Whh + (size_t)(l + 64) * HID);
        #pragma unroll
        for (int j = 0; j < 32; ++j) { whA[j] = ra[j]; whB[j] = rb[j]; }
    }

    // --- projection: rows l, l+64 over d-chunks of 28 + 2-float tail ---
    float zA[16], zB[16];
    #pragma unroll
    for (int t = 0; t < 16; ++t) { zA[t] = 0.f; zB[t] = 0.f; }
    #pragma unroll
    for (int cc = 0; cc < 4; ++cc) {
        const int d0 = cc * 28;
        f32x2 wa[14], wb[14];
        {
            const f32x2* pa = (const f32x2*)&wihl[l*DD + d0];        // 8B-aligned
            const f32x2* pb = (const f32x2*)&wihl[(l + 64)*DD + d0];
            #pragma unroll
            for (int j = 0; j < 14; ++j) { wa[j] = pa[j]; wb[j] = pb[j]; }
        }
        #pragma unroll
        for (int t = 0; t < 16; ++t) {
            const f32x4* sv = (const f32x4*)&seq[t][d0];   // uniform bcast
            float a0=0.f, a1=0.f, b0=0.f, b1=0.f;
            #pragma unroll
            for (int j2 = 0; j2 < 7; ++j2) {
                f32x4 s = sv[j2];
                f32x2 wa0 = wa[2*j2], wa1 = wa[2*j2+1];
                f32x2 wb0 = wb[2*j2], wb1 = wb[2*j2+1];
                a0 = fmaf(wa0.x, s.x, a0); a1 = fmaf(wa0.y, s.y, a1);
                a0 = fmaf(wa1.x, s.z, a0); a1 = fmaf(wa1.y, s.w, a1);
                b0 = fmaf(wb0.x, s.x, b0); b1 = fmaf(wb0.y, s.y, b1);
                b0 = fmaf(wb1.x, s.z, b0); b1 = fmaf(wb1.y, s.w, b1);
            }
            zA[t] += a0 + a1;  zB[t] += b0 + b1;
        }
    }
    {   // tail d = 112, 113
        f32x2 wa = *(const f32x2*)&wihl[l*DD + 112];
        f32x2 wb = *(const f32x2*)&wihl[(l + 64)*DD + 112];
        #pragma unroll
        for (int t = 0; t < 16; ++t) {
            f32x2 s = *(const f32x2*)&seq[t][112];
            zA[t] += wa.x*s.x + wa.y*s.y;
            zB[t] += wb.x*s.x + wb.y*s.y;
        }
    }
    {
        const float biasA = bih[l]      + bhh[l];
        const float biasB = bih[l + 64] + bhh[l + 64];
        #pragma unroll
        for (int t = 0; t < 16; ++t) { zA[t] += biasA; zB[t] += biasB; }
    }

    // --- 16-step recurrence: full-K per lane, h via uniform LDS broadcast ---
    float hsA = 0.f, hsB = 0.f;
    #pragma unroll
    for (int t = 0; t < 16; ++t) {
        const int cur = t & 1, nxt = cur ^ 1;
        const f32x4* h4 = (const f32x4*)hbuf[cur];     // same addr all lanes
        float a0=0.f, a1=0.f, a2=0.f, a3=0.f;
        float b0=0.f, b1=0.f, b2=0.f, b3=0.f;
        #pragma unroll
        for (int j = 0; j < 32; ++j) {
            f32x4 h = h4[j];
            a0 = fmaf(whA[j].x, h.x, a0); a1 = fmaf(whA[j].y, h.y, a1);
            a2 = fmaf(whA[j].z, h.z, a2); a3 = fmaf(whA[j].w, h.w, a3);
            b0 = fmaf(whB[j].x, h.x, b0); b1 = fmaf(whB[j].y, h.y, b1);
            b2 = fmaf(whB[j].z, h.z, b2); b3 = fmaf(whB[j].w, h.w, b3);
        }
        float hA = fast_tanh(zA[t] + ((a0 + a1) + (a2 + a3)));
        float hB = fast_tanh(zB[t] + ((b0 + b1) + (b2 + b3)));
        hsA += hA; hsB += hB;
        hbuf[nxt][l] = hA;  hbuf[nxt][64 + l] = hB;    // conflict-free b32
        __syncthreads();                               // 1-wave barrier
    }
    t_mean[b*HID + l]      = fast_tanh(hsA * (1.f / 16.f));
    t_mean[b*HID + 64 + l] = fast_tanh(hsB * (1.f / 16.f));
}

// ---- k2: block (i, sub) writes out[i, 0, sub*2048 .. +2048) f4 -------------
__global__ __launch_bounds__(256)
void k2_out(const float* __restrict__ s_mean,
            const float* __restrict__ t_mean,
            f32x4* __restrict__ out)
{
    const int i   = blockIdx.x >> 3;           // batch row (512)
    const int sub = blockIdx.x & 7;            // eighth of a row
    const float s = s_mean[i];
    const f32x4* t4 = (const f32x4*)t_mean + sub*2048;
    f32x4*       o  = out + (size_t)i*16384 + sub*2048;
    const int tid = threadIdx.x;
    #pragma unroll
    for (int j = 0; j < 8; ++j) {
        int idx = tid + j*256;
        o[idx] = s * t4[idx];
    }
}

extern "C" void kernel_launch(void* const* d_in, const int* in_sizes, int n_in,
                              void* d_out, int out_size, void* d_ws, size_t ws_size,
                              hipStream_t stream)
{
    const float* x   = (const float*)d_in[0];
    const float* Wih = (const float*)d_in[1];
    const float* Whh = (const float*)d_in[2];
    const float* bih = (const float*)d_in[3];
    const float* bhh = (const float*)d_in[4];

    float* ws     = (float*)d_ws;
    float* s_mean = ws + WS_SMEAN;
    float* t_mean = ws + WS_TMEAN;

    k1_wave<<<dim3(BB), dim3(64), 0, stream>>>(x, Wih, Whh, bih, bhh, s_mean, t_mean);
    k2_out <<<dim3(4096), dim3(256), 0, stream>>>(s_mean, t_mean, (f32x4*)d_out);
}

// Round 16
// 133.539 us; speedup vs baseline: 1.3000x; 1.3000x over previous
//
#include <hip/hip_runtime.h>
#include <math.h>

#define BB   512
#define NBLK 256               // blocks; 1/CU by LDS, grid == #CUs
#define CC   3
#define HH   64
#define WW   32
#define HOUT 38
#define WOUT 16
#define HID  128
#define DD   114               // CC*HOUT
#define SEQQ 36                // seq/h quarter stride (words)
#define SEQP 144               // 4*SEQQ
#define WIHP 132               // Wih LDS row pad (words); 132%32=4 -> banks spread
#define WHHP 132               // Whh LDS row pad (words)
#define NPOOL (CC*HOUT*WOUT)   // 1824

typedef float f32x4 __attribute__((ext_vector_type(4)));

// fast tanh on the serial chain: exact saturation at +/-inf, ~1e-6 abs error
__device__ __forceinline__ float fast_tanh(float u) {
    return 1.f - 2.f / (__expf(2.f * u) + 1.f);
}

// ws layout (bytes): t_mean floats [0, 262144); barrier counter at 262144
#define WS_CNT_OFF 262144

// ---- single fused kernel, software grid barrier ----------------------------
// 256 blocks x 512 threads (8 waves), ~88.5 KB LDS -> exactly 1 block/CU,
// grid == 256 CUs -> all blocks co-resident by construction. Block q handles
// batch pair (2q, 2q+1) with 2x ILP (R13 ownership: wave w rows [16w,16w+16),
// lane kc = K-quarter, shfl_xor combine). After t_mean: device-scope atomic
// barrier, then each block writes 2 output rows (one t_mean read, two rows).
__global__ __launch_bounds__(512, 2)
void k_fused(const float* __restrict__ x,
             const float* __restrict__ Wih,
             const float* __restrict__ Whh,
             const float* __restrict__ bih,
             const float* __restrict__ bhh,
             float* __restrict__ t_mean,
             int*   __restrict__ bar_cnt,
             f32x4* __restrict__ out)
{
    __shared__ __align__(16) float wst[HID * WHHP];   // 67.6 KB; x-pair/Wih/Whh
    __shared__ __align__(16) float seq0[WOUT][SEQP];  // 9.2 KB
    __shared__ __align__(16) float seq1[WOUT][SEQP];  // 9.2 KB
    __shared__ __align__(16) float hb0[2][SEQP];      // 1.2 KB
    __shared__ __align__(16) float hb1[2][SEQP];      // 1.2 KB
    __shared__ float red[2][8];
    __shared__ float sm[2];
    __shared__ int   rowl[HOUT];

    const int tid  = threadIdx.x;
    const int wid  = tid >> 6;                   // wave 0..7
    const int lane = tid & 63;
    const int kl   = (wid << 4) | (lane & 15);   // owned output row 0..127
    const int kc   = lane >> 4;                  // K-quarter 0..3
    const int b0   = 2 * blockIdx.x;             // batch pair

    // --- issue x-pair loads FIRST, then Wih prefetch (stay in flight) ---
    f32x4 xpf[6];
    {
        const f32x4* xg = (const f32x4*)(x + (size_t)b0 * (CC*HH*WW));
        #pragma unroll
        for (int i = 0; i < 6; ++i) xpf[i] = xg[tid + 512*i];
    }
    f32x4 wihpf[7], wihtail;
    {
        const f32x4* wg = (const f32x4*)Wih;          // 3648 f4 total
        #pragma unroll
        for (int i = 0; i < 7; ++i) wihpf[i] = wg[tid + 512*i];
        if (tid < 64) wihtail = wg[3584 + tid];
    }

    // fractional-pool row starts (exact IEEE-f64 numpy match)
    if (tid < HOUT) {
        double alpha = (double)(HH - 2) / (double)(HOUT - 1);
        rowl[tid] = (tid < HOUT - 1)
            ? (int)(floor((tid + 0.5) * alpha) - floor(0.5 * alpha))
            : (HH - 2);
    }
    if (tid < HID) {
        hb0[0][SEQQ*(tid >> 5) + (tid & 31)] = 0.f;
        hb1[0][SEQQ*(tid >> 5) + (tid & 31)] = 0.f;
    }
    if (tid < 448) {                              // zero seq cols 114..127 (q3)
        int s  = tid >= 224;
        int r0 = tid - s*224;
        int t = r0 / 14, o = 18 + r0 % 14;
        if (s) seq1[t][3*SEQQ + o] = 0.f; else seq0[t][3*SEQQ + o] = 0.f;
    }

    // --- write x-pair to LDS (waits only on x; Wih stays in flight) ---
    {
        f32x4* xd = (f32x4*)wst;
        #pragma unroll
        for (int i = 0; i < 6; ++i) xd[tid + 512*i] = xpf[i];
    }
    __syncthreads();                                  // B1

    // --- pool (2x2 fractional max) + exact GELU for BOTH batches ---
    float ps0 = 0.f, ps1 = 0.f;
    #pragma unroll
    for (int it = 0; it < 8; ++it) {
        int idx = tid + it*512;
        if (idx < 2*NPOOL) {
            int bsel = (idx >= NPOOL);
            int r0   = idx - bsel*NPOOL;
            int c  = r0 / (HOUT*WOUT);
            int r  = r0 % (HOUT*WOUT);
            int ho = r / WOUT;
            int wo = r % WOUT;
            const float* p0 = &wst[bsel*(CC*HH*WW) + c*(HH*WW) + rowl[ho]*WW + 2*wo];
            float m = fmaxf(fmaxf(p0[0], p0[1]), fmaxf(p0[WW], p0[WW+1]));
            float a = 0.5f * m * (1.f + erff(m * 0.70710678118654752440f));
            int d = c*HOUT + ho;
            int off = SEQQ*(d >> 5) + (d & 31);
            if (bsel) { ps1 += m; seq1[wo][off] = a; }
            else      { ps0 += m; seq0[wo][off] = a; }
        }
    }
    #pragma unroll
    for (int off = 32; off > 0; off >>= 1) {
        ps0 += __shfl_down(ps0, off);
        ps1 += __shfl_down(ps1, off);
    }
    if (lane == 0) { red[0][wid] = ps0; red[1][wid] = ps1; }
    __syncthreads();                                  // B2 (x reads done; wst free)
    if (tid < 2) {
        float r = 0.f;
        #pragma unroll
        for (int i = 0; i < 8; ++i) r += red[tid][i];
        sm[tid] = r * (1.f / (float)NPOOL);
    }

    // --- Wih: LDS writes from prefetched regs into padded rows [128][132] ---
    #pragma unroll
    for (int i = 0; i < 7; ++i) {
        int j = 4*(tid + 512*i);
        #pragma unroll
        for (int e = 0; e < 4; ++e) {
            int r  = (j + e) / DD;                    // const-div -> magic mul
            int cc = (j + e) - r*DD;
            wst[r*WIHP + cc] = wihpf[i][e];
        }
    }
    if (tid < 64) {
        int j = 4*(3584 + tid);
        #pragma unroll
        for (int e = 0; e < 4; ++e) {
            int r  = (j + e) / DD;
            int cc = (j + e) - r*DD;
            wst[r*WIHP + cc] = wihtail[e];
        }
    }
    for (int j = tid; j < HID*14; j += 512)           // zero cols [114,128)
        wst[(j/14)*WIHP + DD + (j % 14)] = 0.f;
    __syncthreads();                                  // B3

    // wih regs: K-quarter kc of Wih row kl (32 floats)
    f32x4 wih[8];
    {
        const f32x4* wr = (const f32x4*)&wst[kl*WIHP + (kc << 5)];
        #pragma unroll
        for (int dd = 0; dd < 8; ++dd) wih[dd] = wr[dd];
    }

    // --- issue full Whh prefetch (8 f4); latency hides under projection ---
    f32x4 whhpf[8];
    {
        const f32x4* hg = (const f32x4*)Whh;          // 4096 f4
        #pragma unroll
        for (int i = 0; i < 8; ++i) whhpf[i] = hg[tid + 512*i];
    }

    // --- projection for BOTH batches: 2-level shfl completes all lanes ---
    float zr0[WOUT], zr1[WOUT];
    #pragma unroll
    for (int t = 0; t < WOUT; ++t) {
        const f32x4* a4 = (const f32x4*)&seq0[t][kc*SEQQ];
        const f32x4* c4 = (const f32x4*)&seq1[t][kc*SEQQ];
        float s0=0.f, s1=0.f, s2=0.f, s3=0.f;
        float u0=0.f, u1=0.f, u2=0.f, u3=0.f;
        #pragma unroll
        for (int dd = 0; dd < 8; ++dd) {
            f32x4 a = a4[dd], c = c4[dd], w = wih[dd];
            s0 = fmaf(w.x, a.x, s0); u0 = fmaf(w.x, c.x, u0);
            s1 = fmaf(w.y, a.y, s1); u1 = fmaf(w.y, c.y, u1);
            s2 = fmaf(w.z, a.z, s2); u2 = fmaf(w.z, c.z, u2);
            s3 = fmaf(w.w, a.w, s3); u3 = fmaf(w.w, c.w, u3);
        }
        float p = (s0 + s1) + (s2 + s3);
        float q = (u0 + u1) + (u2 + u3);
        p += __shfl_xor(p, 16);
        q += __shfl_xor(q, 16);
        zr0[t] = p + __shfl_xor(p, 32);
        zr1[t] = q + __shfl_xor(q, 32);
    }
    {
        const float bias = bih[kl] + bhh[kl];
        #pragma unroll
        for (int t = 0; t < WOUT; ++t) { zr0[t] += bias; zr1[t] += bias; }
    }
    __syncthreads();                                  // B4 (wih copies done; wst free)

    // --- Whh: ONE staging round into padded rows [128][132] ---
    #pragma unroll
    for (int i = 0; i < 8; ++i) {
        int j4 = tid + 512*i;
        *(f32x4*)&wst[(j4 >> 5)*WHHP + ((j4 & 31) << 2)] = whhpf[i];
    }
    __syncthreads();                                  // B5
    f32x4 whh[8];
    {
        const f32x4* wr = (const f32x4*)&wst[kl*WHHP + (kc << 5)];
        #pragma unroll
        for (int dd = 0; dd < 8; ++dd) whh[dd] = wr[dd];
    }

    // --- 16-step recurrence, 2 batches per barrier (2x ILP) ---
    float hsum0 = 0.f, hsum1 = 0.f;
    #pragma unroll
    for (int t = 0; t < WOUT; ++t) {
        const int cur = t & 1, nxt = cur ^ 1;
        const f32x4* h40 = (const f32x4*)&hb0[cur][kc*SEQQ];
        const f32x4* h41 = (const f32x4*)&hb1[cur][kc*SEQQ];
        float s0=0.f, s1=0.f, s2=0.f, s3=0.f;
        float u0=0.f, u1=0.f, u2=0.f, u3=0.f;
        #pragma unroll
        for (int dd = 0; dd < 8; ++dd) {
            f32x4 hv = h40[dd], gv = h41[dd], w = whh[dd];
            s0 = fmaf(w.x, hv.x, s0); u0 = fmaf(w.x, gv.x, u0);
            s1 = fmaf(w.y, hv.y, s1); u1 = fmaf(w.y, gv.y, u1);
            s2 = fmaf(w.z, hv.z, s2); u2 = fmaf(w.z, gv.z, u2);
            s3 = fmaf(w.w, hv.w, s3); u3 = fmaf(w.w, gv.w, u3);
        }
        float p = (s0 + s1) + (s2 + s3);
        float q = (u0 + u1) + (u2 + u3);
        p += __shfl_xor(p, 16);
        q += __shfl_xor(q, 16);
        float v0 = zr0[t] + p + __shfl_xor(p, 32);
        float v1 = zr1[t] + q + __shfl_xor(q, 32);
        float hn0 = fast_tanh(v0);
        float hn1 = fast_tanh(v1);
        hsum0 += hn0; hsum1 += hn1;
        if (kc == 0) {
            int off = SEQQ*(kl >> 5) + (kl & 31);
            hb0[nxt][off] = hn0;
            hb1[nxt][off] = hn1;
        }
        __syncthreads();                              // one barrier, two batches
    }
    if (kc == 0) {
        t_mean[(b0    )*HID + kl] = fast_tanh(hsum0 * (1.f / 16.f));
        t_mean[(b0 + 1)*HID + kl] = fast_tanh(hsum1 * (1.f / 16.f));
    }

    // --- software grid barrier (all 256 blocks resident by construction) ---
    __threadfence();                                  // release t_mean stores
    __syncthreads();
    if (tid == 0) {
        __hip_atomic_fetch_add(bar_cnt, 1, __ATOMIC_ACQ_REL, __HIP_MEMORY_SCOPE_AGENT);
        int iters = 0;
        while (__hip_atomic_load(bar_cnt, __ATOMIC_ACQUIRE, __HIP_MEMORY_SCOPE_AGENT) < NBLK
               && iters < 2000000) {
            __builtin_amdgcn_s_sleep(8);
            ++iters;                                  // bounded spin: hang-guard
        }
    }
    __syncthreads();
    __threadfence();                                  // acquire: invalidate caches

    // --- phase 2: one t_mean read serves TWO output rows (b0, b0+1) ---
    {
        const float  s0 = sm[0], s1 = sm[1];
        const f32x4* t4 = (const f32x4*)t_mean;       // 16384 f4, L2-warm
        f32x4* o0 = out + (size_t)b0 * 16384;
        f32x4* o1 = o0 + 16384;
        #pragma unroll
        for (int j = 0; j < 32; ++j) {
            int idx = tid + 512*j;
            f32x4 v = t4[idx];
            o0[idx] = s0 * v;
            o1[idx] = s1 * v;
        }
    }
}

extern "C" void kernel_launch(void* const* d_in, const int* in_sizes, int n_in,
                              void* d_out, int out_size, void* d_ws, size_t ws_size,
                              hipStream_t stream)
{
    const float* x   = (const float*)d_in[0];
    const float* Wih = (const float*)d_in[1];
    const float* Whh = (const float*)d_in[2];
    const float* bih = (const float*)d_in[3];
    const float* bhh = (const float*)d_in[4];

    float* t_mean  = (float*)d_ws;
    int*   bar_cnt = (int*)((char*)d_ws + WS_CNT_OFF);

    hipMemsetAsync(bar_cnt, 0, sizeof(int), stream);  // zero barrier each call
    k_fused<<<dim3(NBLK), dim3(512), 0, stream>>>(
        x, Wih, Whh, bih, bhh, t_mean, bar_cnt, (f32x4*)d_out);
}